// Round 7
// baseline (366.989 us; speedup 1.0000x reference)
//
#include <hip/hip_runtime.h>

typedef __attribute__((ext_vector_type(8))) short bf16x8;   // MFMA A/B frag
typedef __attribute__((ext_vector_type(4))) float f32x4;    // MFMA C/D frag
typedef __attribute__((ext_vector_type(4))) short s16x4;    // 4 bf16 (8 B)

__device__ __forceinline__ unsigned cvt_pk(float lo, float hi) {
  unsigned r;
  asm("v_cvt_pk_bf16_f32 %0, %1, %2" : "=v"(r) : "v"(lo), "v"(hi));
  return r;
}
__device__ __forceinline__ float bf2f(short s) {
  return __uint_as_float(((unsigned)(unsigned short)s) << 16);
}
__device__ __forceinline__ float sigm(float z) {
  return __builtin_amdgcn_rcpf(1.f + __builtin_amdgcn_exp2f(-1.44269504089f * z));
}
__device__ __forceinline__ float tanh_(float z) {
  return 1.f - 2.f * __builtin_amdgcn_rcpf(1.f + __builtin_amdgcn_exp2f(2.88539008178f * z));
}

// ---------- geometry ----------
// ws per component: 4 matrices as A-operand fragments (W^T strips), bf16.
//   mat m in {W1a(out),W1b(x),W2,W3}: frag (w,kc,lane) 16 B at ((w*4+kc)*64+l)*16
#define WS_MAT 32768
#define WS_COMP 131072
// 64 rows per block
#define NODE_BLOCKS 782
#define EDGE_BLOCKS 1563
#define GLOB_BLOCKS 8
#define NBLOCKS (NODE_BLOCKS + EDGE_BLOCKS + GLOB_BLOCKS)   // 2353

// swizzled byte offset within a [64 rows][256 B] LDS tile
#define SWZ(row, byte) ((row) * 256 + ((byte) ^ (((row) & 7) << 4)))
#define XBUF_B 16384
#define OBUF_B 16384
#define BIAS_OFF 81920            // 3*16384 + 2*16384
#define SMEM_B 83456

__global__ __launch_bounds__(256) void prep_weights(
    const float* __restrict__ W1, const float* __restrict__ W2,
    const float* __restrict__ W3, unsigned char* __restrict__ wsc) {
  const int m = blockIdx.x;   // 0=W1a 1=W1b 2=W2 3=W3
  const float* src; int rowoff = 0;
  if (m == 0)      { src = W1; }
  else if (m == 1) { src = W1; rowoff = 128; }
  else if (m == 2) { src = W2; }
  else             { src = W3; }
  short* dst = (short*)(wsc + (size_t)m * WS_MAT);
  for (int fi = threadIdx.x; fi < 2048; fi += 256) {
    int w = fi >> 8, kc = (fi >> 6) & 3, lane = fi & 63;
    int cc = lane & 15, gg = lane >> 4;
    int wcol = 16 * w + cc;
    int kb = 32 * kc + 8 * gg + rowoff;
    union { bf16x8 h; unsigned u[4]; } v;
#pragma unroll
    for (int j = 0; j < 4; ++j)
      v.u[j] = cvt_pk(src[(size_t)(kb + 2 * j) * 128 + wcol],
                      src[(size_t)(kb + 2 * j + 1) * 128 + wcol]);
    *(bf16x8*)(dst + (size_t)fi * 8) = v.h;
  }
}

// x-only precompute for one 16-row tile (u, g3, aAx for the NEXT step)
__device__ __forceinline__ void pre_tile(
    const char* xb, const float* blds, int row, int g, int w,
    const bf16x8* w1b, const bf16x8* w2, const bf16x8* w3,
    f32x4& u, f32x4& g3, f32x4& aAx) {
  bf16x8 xf[4];
#pragma unroll
  for (int kc = 0; kc < 4; ++kc)
    xf[kc] = *(const bf16x8*)(xb + SWZ(row, 64 * kc + 16 * g));
  s16x4 xe4 = *(const s16x4*)(xb + SWZ(row, 32 * w + 8 * g));
  const int bo = 16 * w + 4 * g;
  f32x4 aX = *(const f32x4*)(blds + bo);
  f32x4 aB = *(const f32x4*)(blds + 128 + bo);
  f32x4 aC = *(const f32x4*)(blds + 256 + bo);
#pragma unroll
  for (int kc = 0; kc < 4; ++kc) {
    aX = __builtin_amdgcn_mfma_f32_16x16x32_bf16(w1b[kc], xf[kc], aX, 0, 0, 0);
    aB = __builtin_amdgcn_mfma_f32_16x16x32_bf16(w2[kc],  xf[kc], aB, 0, 0, 0);
    aC = __builtin_amdgcn_mfma_f32_16x16x32_bf16(w3[kc],  xf[kc], aC, 0, 0, 0);
  }
#pragma unroll
  for (int ri = 0; ri < 4; ++ri) {
    u[ri]  = sigm(aB[ri]) * tanh_(bf2f(xe4[ri]));
    g3[ri] = sigm(aC[ri]);
  }
  aAx = aX;
}

// serial (recurrent) part for one 16-row tile; writes out(t) unless last step
__device__ __forceinline__ void ser_tile(
    const char* ofsrc, char* obw, bool wr, int row, int g, int w,
    const bf16x8* w1a, f32x4 aAx, f32x4 u, f32x4 g3,
    f32x4& st) {
  bf16x8 of[4];
#pragma unroll
  for (int kc = 0; kc < 4; ++kc)
    of[kc] = *(const bf16x8*)(ofsrc + SWZ(row, 64 * kc + 16 * g));
  f32x4 aA = aAx;   // = x@W1b + b1 (precomputed)
#pragma unroll
  for (int kc = 0; kc < 4; ++kc)
    aA = __builtin_amdgcn_mfma_f32_16x16x32_bf16(w1a[kc], of[kc], aA, 0, 0, 0);
  f32x4 ov;
#pragma unroll
  for (int ri = 0; ri < 4; ++ri) {
    float fgt = sigm(aA[ri]);
    st[ri] = st[ri] * fgt + u[ri];
    ov[ri] = tanh_(st[ri]) * g3[ri];
  }
  if (wr) {
    union { s16x4 v; unsigned uu[2]; } ob;
    ob.uu[0] = cvt_pk(ov[0], ov[1]);
    ob.uu[1] = cvt_pk(ov[2], ov[3]);
    *(s16x4*)(obw + SWZ(row, 32 * w + 8 * g)) = ob.v;
  }
}

__global__ __launch_bounds__(512) void glstm(
    const float* __restrict__ xs, const float* __restrict__ es,
    const float* __restrict__ gs, const unsigned char* __restrict__ ws,
    const float* __restrict__ b1n, const float* __restrict__ b2n, const float* __restrict__ b3n,
    const float* __restrict__ b1e, const float* __restrict__ b2e, const float* __restrict__ b3e,
    const float* __restrict__ b1g, const float* __restrict__ b2g, const float* __restrict__ b3g,
    float* __restrict__ dout) {
  // LDS: 3 x-buffers (16 KB) + 2 out-buffers (16 KB) + biases (1.5 KB) = 81.5 KB
  __shared__ __align__(16) unsigned char smem[SMEM_B];

  const int bid = blockIdx.x, tid = threadIdx.x;
  const float* X; const float *B1, *B2, *B3; float *S, *O; int M, unit, comp;
  if (bid < NODE_BLOCKS) {
    X = xs; M = 50000;  S = dout;              O = dout + 19265536L;
    unit = bid; comp = 0; B1 = b1n; B2 = b2n; B3 = b3n;
  } else if (bid < NODE_BLOCKS + EDGE_BLOCKS) {
    X = es; M = 100000; S = dout + 6400000L;   O = dout + 25665536L;
    unit = bid - NODE_BLOCKS; comp = 1; B1 = b1e; B2 = b2e; B3 = b3e;
  } else {
    X = gs; M = 512;    S = dout + 19200000L;  O = dout + 38465536L;
    unit = bid - (NODE_BLOCKS + EDGE_BLOCKS); comp = 2; B1 = b1g; B2 = b2g; B3 = b3g;
  }

  const int w = tid >> 6, l = tid & 63, c = l & 15, g = l >> 4;
  const int Ra = unit * 64;
  const bool val1 = (Ra + 16) < M, val2 = (Ra + 32) < M, val3 = (Ra + 48) < M;

  // weights -> registers (once)
  bf16x8 wA[4][4];
  {
    const short* wsrc = (const short*)(ws + (size_t)comp * WS_COMP);
#pragma unroll
    for (int m = 0; m < 4; ++m)
#pragma unroll
      for (int kc = 0; kc < 4; ++kc)
        wA[m][kc] = *(const bf16x8*)(wsrc + (size_t)m * 16384 + ((w * 4 + kc) * 64 + l) * 8);
  }

  char* xb0 = (char*)smem;
  char* xb1 = (char*)smem + XBUF_B;
  char* xb2 = (char*)smem + 2 * XBUF_B;
  char* ob0 = (char*)smem + 3 * XBUF_B;
  char* ob1 = (char*)smem + 3 * XBUF_B + OBUF_B;
  float* blds = (float*)(smem + BIAS_OFF);

  // biases -> LDS (keeps them out of persistent VGPRs)
  if (tid < 128) {
    blds[tid]       = B1[tid];
    blds[128 + tid] = B2[tid];
    blds[256 + tid] = B3[tid];
  }

  const int srow = tid >> 4;              // 0..31; handles rows srow, srow+32
  const int sbyte = (tid & 15) * 16;      // bf16 byte col
  const int scol = (tid & 15) * 8;        // f32 col
  const bool sv0 = (Ra + srow) < M;
  const bool sv1 = (Ra + 32 + srow) < M;

  // ---- prologue: stage x(0)->xb0, x(1)->xb1 (rows srow and srow+32)
  if (sv0) {
    const float* p0 = X + (size_t)(Ra + srow) * 128 + scol;
    const float* p1 = p0 + (size_t)M * 128;
    f32x4 a0 = *(const f32x4*)p0, a1 = *(const f32x4*)(p0 + 4);
    f32x4 a2 = *(const f32x4*)p1, a3 = *(const f32x4*)(p1 + 4);
    union { bf16x8 h; unsigned u[4]; } o;
    o.u[0] = cvt_pk(a0[0], a0[1]); o.u[1] = cvt_pk(a0[2], a0[3]);
    o.u[2] = cvt_pk(a1[0], a1[1]); o.u[3] = cvt_pk(a1[2], a1[3]);
    *(bf16x8*)(xb0 + SWZ(srow, sbyte)) = o.h;
    o.u[0] = cvt_pk(a2[0], a2[1]); o.u[1] = cvt_pk(a2[2], a2[3]);
    o.u[2] = cvt_pk(a3[0], a3[1]); o.u[3] = cvt_pk(a3[2], a3[3]);
    *(bf16x8*)(xb1 + SWZ(srow, sbyte)) = o.h;
  }
  if (sv1) {
    const int r = srow + 32;
    const float* p0 = X + (size_t)(Ra + r) * 128 + scol;
    const float* p1 = p0 + (size_t)M * 128;
    f32x4 a0 = *(const f32x4*)p0, a1 = *(const f32x4*)(p0 + 4);
    f32x4 a2 = *(const f32x4*)p1, a3 = *(const f32x4*)(p1 + 4);
    union { bf16x8 h; unsigned u[4]; } o;
    o.u[0] = cvt_pk(a0[0], a0[1]); o.u[1] = cvt_pk(a0[2], a0[3]);
    o.u[2] = cvt_pk(a1[0], a1[1]); o.u[3] = cvt_pk(a1[2], a1[3]);
    *(bf16x8*)(xb0 + SWZ(r, sbyte)) = o.h;
    o.u[0] = cvt_pk(a2[0], a2[1]); o.u[1] = cvt_pk(a2[2], a2[3]);
    o.u[2] = cvt_pk(a3[0], a3[1]); o.u[3] = cvt_pk(a3[2], a3[3]);
    *(bf16x8*)(xb1 + SWZ(r, sbyte)) = o.h;
  }
  __syncthreads();

  // state init = x[0] (bf16-rounded); precompute step-0 x-terms from xb0
  f32x4 st[4], uu[4], g3[4], ax[4];
#pragma unroll
  for (int i = 0; i < 4; ++i) {
    st[i] = (f32x4){0.f, 0.f, 0.f, 0.f};
    uu[i] = st[i]; g3[i] = st[i]; ax[i] = st[i];
  }
  {
    const bool val[4] = {true, val1, val2, val3};
#pragma unroll
    for (int i = 0; i < 4; ++i) if (val[i]) {
      s16x4 e = *(const s16x4*)(xb0 + SWZ(16 * i + c, 32 * w + 8 * g));
#pragma unroll
      for (int ri = 0; ri < 4; ++ri) st[i][ri] = bf2f(e[ri]);
      pre_tile(xb0, blds, 16 * i + c, g, w, wA[1], wA[2], wA[3], uu[i], g3[i], ax[i]);
    }
  }

  // rotating x buffers: xr = x(t+1), xw = target for x(t+2), xsp = x(t) (x(0) at t=0)
  char* xr = xb1; char* xw = xb2; char* xsp = xb0;
  char* orf = ob0; char* owf = ob1;

#pragma unroll 1
  for (int t = 0; t < 8; ++t) {
    // prefetch x(t+2): issue loads early, LDS-write at step end
    f32x4 pa0, pa1, pb0, pb1;
    const bool pf = (t < 6);
    if (pf && sv0) {
      const float* p = X + ((size_t)(t + 2) * M + Ra + srow) * 128 + scol;
      pa0 = *(const f32x4*)p; pa1 = *(const f32x4*)(p + 4);
    }
    if (pf && sv1) {
      const float* p = X + ((size_t)(t + 2) * M + Ra + srow + 32) * 128 + scol;
      pb0 = *(const f32x4*)p; pb1 = *(const f32x4*)(p + 4);
    }

    // serial recurrent part (of = out(t-1); at t=0 out(-1)=x(0) in xsp)
    const char* ofs = (t == 0) ? (const char*)xsp : (const char*)orf;
    const bool wr = (t < 7);
    {
      const bool val[4] = {true, val1, val2, val3};
#pragma unroll
      for (int i = 0; i < 4; ++i) if (val[i])
        ser_tile(ofs, owf, wr, 16 * i + c, g, w, wA[0], ax[i], uu[i], g3[i], st[i]);

      // precompute x-terms for step t+1 (independent of the serial chain)
      if (t < 7) {
#pragma unroll
        for (int i = 0; i < 4; ++i) if (val[i])
          pre_tile(xr, blds, 16 * i + c, g, w, wA[1], wA[2], wA[3], uu[i], g3[i], ax[i]);
      }
    }

    // write staged x(t+2)
    if (pf && sv0) {
      union { bf16x8 h; unsigned u[4]; } o;
      o.u[0] = cvt_pk(pa0[0], pa0[1]); o.u[1] = cvt_pk(pa0[2], pa0[3]);
      o.u[2] = cvt_pk(pa1[0], pa1[1]); o.u[3] = cvt_pk(pa1[2], pa1[3]);
      *(bf16x8*)(xw + SWZ(srow, sbyte)) = o.h;
    }
    if (pf && sv1) {
      union { bf16x8 h; unsigned u[4]; } o;
      o.u[0] = cvt_pk(pb0[0], pb0[1]); o.u[1] = cvt_pk(pb0[2], pb0[3]);
      o.u[2] = cvt_pk(pb1[0], pb1[1]); o.u[3] = cvt_pk(pb1[2], pb1[3]);
      *(bf16x8*)(xw + SWZ(srow + 32, sbyte)) = o.h;
    }
    __syncthreads();

    // rotate buffers
    char* tx = xsp; xsp = xr; xr = xw; xw = tx;
    char* to = orf; orf = owf; owf = to;
  }

  // ---- epilogue: out = tanh(st)*g3 (g3 holds step-7 values), store f32
  {
    const bool val[4] = {true, val1, val2, val3};
#pragma unroll
    for (int i = 0; i < 4; ++i) if (val[i]) {
      f32x4 ov;
#pragma unroll
      for (int ri = 0; ri < 4; ++ri) ov[ri] = tanh_(st[i][ri]) * g3[i][ri];
      size_t o = (size_t)(Ra + 16 * i + c) * 128 + 16 * w + 4 * g;
      *(f32x4*)(S + o) = st[i];
      *(f32x4*)(O + o) = ov;
    }
  }
}

extern "C" void kernel_launch(void* const* d_in, const int* in_sizes, int n_in,
                              void* d_out, int out_size, void* d_ws, size_t ws_size,
                              hipStream_t stream) {
  (void)in_sizes; (void)n_in; (void)out_size; (void)ws_size;
  const float* xs = (const float*)d_in[0];
  const float* es = (const float*)d_in[1];
  const float* gs = (const float*)d_in[2];
  unsigned char* ws = (unsigned char*)d_ws;

  for (int comp = 0; comp < 3; ++comp) {
    const float* W1 = (const float*)d_in[3 + comp * 6 + 0];
    const float* W2 = (const float*)d_in[3 + comp * 6 + 2];
    const float* W3 = (const float*)d_in[3 + comp * 6 + 4];
    prep_weights<<<4, 256, 0, stream>>>(W1, W2, W3, ws + (size_t)comp * WS_COMP);
  }
  glstm<<<NBLOCKS, 512, 0, stream>>>(
      xs, es, gs, ws,
      (const float*)d_in[4],  (const float*)d_in[6],  (const float*)d_in[8],
      (const float*)d_in[10], (const float*)d_in[12], (const float*)d_in[14],
      (const float*)d_in[16], (const float*)d_in[18], (const float*)d_in[20],
      (float*)d_out);
}

// Round 8
// 284.937 us; speedup vs baseline: 1.2880x; 1.2880x over previous
//
#include <hip/hip_runtime.h>

typedef __attribute__((ext_vector_type(8))) short bf16x8;   // MFMA A/B frag
typedef __attribute__((ext_vector_type(4))) float f32x4;    // MFMA C/D frag
typedef __attribute__((ext_vector_type(4))) short s16x4;    // 4 bf16 (8 B)

__device__ __forceinline__ unsigned cvt_pk(float lo, float hi) {
  unsigned r;
  asm("v_cvt_pk_bf16_f32 %0, %1, %2" : "=v"(r) : "v"(lo), "v"(hi));
  return r;
}
__device__ __forceinline__ float bf2f(short s) {
  return __uint_as_float(((unsigned)(unsigned short)s) << 16);
}
__device__ __forceinline__ float sigm(float z) {
  return __builtin_amdgcn_rcpf(1.f + __builtin_amdgcn_exp2f(-1.44269504089f * z));
}
__device__ __forceinline__ float tanh_(float z) {
  return 1.f - 2.f * __builtin_amdgcn_rcpf(1.f + __builtin_amdgcn_exp2f(2.88539008178f * z));
}

// ---------- geometry ----------
// ws per component: 4 matrices as A-operand fragments (W^T strips), bf16.
//   mat m in {W1a(out),W1b(x),W2,W3}: frag (w,kc,lane) 16 B at ((w*4+kc)*64+l)*16
#define WS_MAT 32768
#define WS_COMP 131072
// 16 rows per block (all M divisible by 16 -> no validity predicates)
#define NODE_BLOCKS 3125
#define EDGE_BLOCKS 6250
#define GLOB_BLOCKS 32
#define NBLOCKS (NODE_BLOCKS + EDGE_BLOCKS + GLOB_BLOCKS)   // 9407

// swizzled byte offset within a [16 rows][256 B] LDS tile
#define SWZ(row, byte) ((row) * 256 + ((byte) ^ (((row) & 7) << 4)))
#define XBUF_B 4096
#define OBUF_B 4096
#define BIAS_OFF 20480            // 3*4096 + 2*4096
#define SMEM_B 22016              // + 1.5 KB biases

__global__ __launch_bounds__(256) void prep_weights(
    const float* __restrict__ W1, const float* __restrict__ W2,
    const float* __restrict__ W3, unsigned char* __restrict__ wsc) {
  const int m = blockIdx.x;   // 0=W1a 1=W1b 2=W2 3=W3
  const float* src; int rowoff = 0;
  if (m == 0)      { src = W1; }
  else if (m == 1) { src = W1; rowoff = 128; }
  else if (m == 2) { src = W2; }
  else             { src = W3; }
  short* dst = (short*)(wsc + (size_t)m * WS_MAT);
  for (int fi = threadIdx.x; fi < 2048; fi += 256) {
    int w = fi >> 8, kc = (fi >> 6) & 3, lane = fi & 63;
    int cc = lane & 15, gg = lane >> 4;
    int wcol = 16 * w + cc;
    int kb = 32 * kc + 8 * gg + rowoff;
    union { bf16x8 h; unsigned u[4]; } v;
#pragma unroll
    for (int j = 0; j < 4; ++j)
      v.u[j] = cvt_pk(src[(size_t)(kb + 2 * j) * 128 + wcol],
                      src[(size_t)(kb + 2 * j + 1) * 128 + wcol]);
    *(bf16x8*)(dst + (size_t)fi * 8) = v.h;
  }
}

// x-only precompute for one 16-row tile (u, g3, aAx for the NEXT step)
__device__ __forceinline__ void pre_tile(
    const char* xb, const float* blds, int row, int g, int w,
    const bf16x8* w1b, const bf16x8* w2, const bf16x8* w3,
    f32x4& u, f32x4& g3, f32x4& aAx) {
  bf16x8 xf[4];
#pragma unroll
  for (int kc = 0; kc < 4; ++kc)
    xf[kc] = *(const bf16x8*)(xb + SWZ(row, 64 * kc + 16 * g));
  s16x4 xe4 = *(const s16x4*)(xb + SWZ(row, 32 * w + 8 * g));
  const int bo = 16 * w + 4 * g;
  f32x4 aX = *(const f32x4*)(blds + bo);
  f32x4 aB = *(const f32x4*)(blds + 128 + bo);
  f32x4 aC = *(const f32x4*)(blds + 256 + bo);
#pragma unroll
  for (int kc = 0; kc < 4; ++kc) {
    aX = __builtin_amdgcn_mfma_f32_16x16x32_bf16(w1b[kc], xf[kc], aX, 0, 0, 0);
    aB = __builtin_amdgcn_mfma_f32_16x16x32_bf16(w2[kc],  xf[kc], aB, 0, 0, 0);
    aC = __builtin_amdgcn_mfma_f32_16x16x32_bf16(w3[kc],  xf[kc], aC, 0, 0, 0);
  }
#pragma unroll
  for (int ri = 0; ri < 4; ++ri) {
    u[ri]  = sigm(aB[ri]) * tanh_(bf2f(xe4[ri]));
    g3[ri] = sigm(aC[ri]);
  }
  aAx = aX;
}

// serial (recurrent) part for one 16-row tile; writes out(t) unless last step
__device__ __forceinline__ void ser_tile(
    const char* ofsrc, char* obw, bool wr, int row, int g, int w,
    const bf16x8* w1a, f32x4 aAx, f32x4 u, f32x4 g3,
    f32x4& st) {
  bf16x8 of[4];
#pragma unroll
  for (int kc = 0; kc < 4; ++kc)
    of[kc] = *(const bf16x8*)(ofsrc + SWZ(row, 64 * kc + 16 * g));
  f32x4 aA = aAx;   // = x@W1b + b1 (precomputed)
#pragma unroll
  for (int kc = 0; kc < 4; ++kc)
    aA = __builtin_amdgcn_mfma_f32_16x16x32_bf16(w1a[kc], of[kc], aA, 0, 0, 0);
  f32x4 ov;
#pragma unroll
  for (int ri = 0; ri < 4; ++ri) {
    float fgt = sigm(aA[ri]);
    st[ri] = st[ri] * fgt + u[ri];
    ov[ri] = tanh_(st[ri]) * g3[ri];
  }
  if (wr) {
    union { s16x4 v; unsigned uu[2]; } ob;
    ob.uu[0] = cvt_pk(ov[0], ov[1]);
    ob.uu[1] = cvt_pk(ov[2], ov[3]);
    *(s16x4*)(obw + SWZ(row, 32 * w + 8 * g)) = ob.v;
  }
}

__global__ __launch_bounds__(512, 4) void glstm(
    const float* __restrict__ xs, const float* __restrict__ es,
    const float* __restrict__ gs, const unsigned char* __restrict__ ws,
    const float* __restrict__ b1n, const float* __restrict__ b2n, const float* __restrict__ b3n,
    const float* __restrict__ b1e, const float* __restrict__ b2e, const float* __restrict__ b3e,
    const float* __restrict__ b1g, const float* __restrict__ b2g, const float* __restrict__ b3g,
    float* __restrict__ dout) {
  // LDS: 3 x-buffers (12 KB) + 2 out-buffers (8 KB) + biases (1.5 KB) = 21.5 KB
  __shared__ __align__(16) unsigned char smem[SMEM_B];

  const int bid = blockIdx.x, tid = threadIdx.x;
  const float* X; const float *B1, *B2, *B3; float *S, *O; int M, unit, comp;
  if (bid < NODE_BLOCKS) {
    X = xs; M = 50000;  S = dout;              O = dout + 19265536L;
    unit = bid; comp = 0; B1 = b1n; B2 = b2n; B3 = b3n;
  } else if (bid < NODE_BLOCKS + EDGE_BLOCKS) {
    X = es; M = 100000; S = dout + 6400000L;   O = dout + 25665536L;
    unit = bid - NODE_BLOCKS; comp = 1; B1 = b1e; B2 = b2e; B3 = b3e;
  } else {
    X = gs; M = 512;    S = dout + 19200000L;  O = dout + 38465536L;
    unit = bid - (NODE_BLOCKS + EDGE_BLOCKS); comp = 2; B1 = b1g; B2 = b2g; B3 = b3g;
  }

  const int w = tid >> 6, l = tid & 63, c = l & 15, g = l >> 4;
  const int Ra = unit * 16;

  // weights -> registers (once; reused across all rows and steps)
  bf16x8 wA[4][4];
  {
    const short* wsrc = (const short*)(ws + (size_t)comp * WS_COMP);
#pragma unroll
    for (int m = 0; m < 4; ++m)
#pragma unroll
      for (int kc = 0; kc < 4; ++kc)
        wA[m][kc] = *(const bf16x8*)(wsrc + (size_t)m * 16384 + ((w * 4 + kc) * 64 + l) * 8);
  }

  char* xb0 = (char*)smem;
  char* xb1 = (char*)smem + XBUF_B;
  char* xb2 = (char*)smem + 2 * XBUF_B;
  char* ob0 = (char*)smem + 3 * XBUF_B;
  char* ob1 = (char*)smem + 3 * XBUF_B + OBUF_B;
  float* blds = (float*)(smem + BIAS_OFF);

  // biases -> LDS (keeps them out of persistent VGPRs)
  if (tid < 128) {
    blds[tid]       = B1[tid];
    blds[128 + tid] = B2[tid];
    blds[256 + tid] = B3[tid];
  }

  const int srow = tid >> 5;              // 0..15
  const int sbyte = (tid & 31) * 8;       // bf16 byte col (8 B per thread)
  const int scol = (tid & 31) * 4;        // f32 col

  // ---- prologue: stage x(0)->xb0, x(1)->xb1 (4 f32 per thread per buffer)
  {
    const float* p0 = X + (size_t)(Ra + srow) * 128 + scol;
    const float* p1 = p0 + (size_t)M * 128;
    f32x4 a0 = *(const f32x4*)p0;
    f32x4 a1 = *(const f32x4*)p1;
    union { s16x4 v; unsigned u[2]; } o;
    o.u[0] = cvt_pk(a0[0], a0[1]); o.u[1] = cvt_pk(a0[2], a0[3]);
    *(s16x4*)(xb0 + SWZ(srow, sbyte)) = o.v;
    o.u[0] = cvt_pk(a1[0], a1[1]); o.u[1] = cvt_pk(a1[2], a1[3]);
    *(s16x4*)(xb1 + SWZ(srow, sbyte)) = o.v;
  }
  __syncthreads();

  // state init = x[0] (bf16-rounded); precompute step-0 x-terms from xb0
  f32x4 st, uu, g3, ax;
  {
    s16x4 e = *(const s16x4*)(xb0 + SWZ(c, 32 * w + 8 * g));
#pragma unroll
    for (int ri = 0; ri < 4; ++ri) st[ri] = bf2f(e[ri]);
  }
  pre_tile(xb0, blds, c, g, w, wA[1], wA[2], wA[3], uu, g3, ax);

  // rotating x buffers: xr = x(t+1), xw = target for x(t+2), xsp = x(t)
  char* xr = xb1; char* xw = xb2; char* xsp = xb0;
  char* orf = ob0; char* owf = ob1;

#pragma unroll 1
  for (int t = 0; t < 8; ++t) {
    // prefetch x(t+2): issue load early, LDS-write at step end
    f32x4 pa;
    const bool pf = (t < 6);
    if (pf) {
      const float* p = X + ((size_t)(t + 2) * M + Ra + srow) * 128 + scol;
      pa = *(const f32x4*)p;
    }

    // serial recurrent part (of = out(t-1); at t=0 out(-1)=x(0) in xsp)
    const char* ofs = (t == 0) ? (const char*)xsp : (const char*)orf;
    const bool wr = (t < 7);
    ser_tile(ofs, owf, wr, c, g, w, wA[0], ax, uu, g3, st);

    // precompute x-terms for step t+1 (independent of the serial chain)
    if (t < 7)
      pre_tile(xr, blds, c, g, w, wA[1], wA[2], wA[3], uu, g3, ax);

    // write staged x(t+2)
    if (pf) {
      union { s16x4 v; unsigned u[2]; } o;
      o.u[0] = cvt_pk(pa[0], pa[1]); o.u[1] = cvt_pk(pa[2], pa[3]);
      *(s16x4*)(xw + SWZ(srow, sbyte)) = o.v;
    }
    __syncthreads();

    // rotate buffers
    char* tx = xsp; xsp = xr; xr = xw; xw = tx;
    char* to = orf; orf = owf; owf = to;
  }

  // ---- epilogue: out = tanh(st)*g3 (g3 holds step-7 values), store f32
  {
    f32x4 ov;
#pragma unroll
    for (int ri = 0; ri < 4; ++ri) ov[ri] = tanh_(st[ri]) * g3[ri];
    size_t o = (size_t)(Ra + c) * 128 + 16 * w + 4 * g;
    *(f32x4*)(S + o) = st;
    *(f32x4*)(O + o) = ov;
  }
}

extern "C" void kernel_launch(void* const* d_in, const int* in_sizes, int n_in,
                              void* d_out, int out_size, void* d_ws, size_t ws_size,
                              hipStream_t stream) {
  (void)in_sizes; (void)n_in; (void)out_size; (void)ws_size;
  const float* xs = (const float*)d_in[0];
  const float* es = (const float*)d_in[1];
  const float* gs = (const float*)d_in[2];
  unsigned char* ws = (unsigned char*)d_ws;

  for (int comp = 0; comp < 3; ++comp) {
    const float* W1 = (const float*)d_in[3 + comp * 6 + 0];
    const float* W2 = (const float*)d_in[3 + comp * 6 + 2];
    const float* W3 = (const float*)d_in[3 + comp * 6 + 4];
    prep_weights<<<4, 256, 0, stream>>>(W1, W2, W3, ws + (size_t)comp * WS_COMP);
  }
  glstm<<<NBLOCKS, 512, 0, stream>>>(
      xs, es, gs, ws,
      (const float*)d_in[4],  (const float*)d_in[6],  (const float*)d_in[8],
      (const float*)d_in[10], (const float*)d_in[12], (const float*)d_in[14],
      (const float*)d_in[16], (const float*)d_in[18], (const float*)d_in[20],
      (float*)d_out);
}